// Round 2
// baseline (871.815 us; speedup 1.0000x reference)
//
#include <hip/hip_runtime.h>

// RNN: h_t = relu(x_t @ W_ih^T + b_ih + b_hh + h_{t-1} @ W_hh^T); y_t = h_t @ W_out^T + b_out
// B=512, T=2000, D=3, H=50.
// R2: TWO batch elements per wave, instruction streams interleaved -> 2-deep ILP
// hides readlane->fmac SGPR hazards and fmac chain latency (R1 was 487 cyc/step vs
// 224 issue-floor with 1-deep ILP). Grid 256 blocks = 1 wave/CU, all CUs busy.
// Lane i owns W_hh row i (shared across both batches). h broadcast via v_readlane.
// Output projection per 50-step tile via LDS transpose (stride 51 = conflict-free).

#define BB 512
#define TT 2000
#define DD 3
#define HH 50
#define TILE 50      // divides TT exactly (40 tiles)
#define HSTR 51      // odd stride -> conflict-free column reads

__device__ __forceinline__ float bcast(float v, int lane) {
    return __int_as_float(__builtin_amdgcn_readlane(__float_as_int(v), lane));
}

__global__ __launch_bounds__(64) void rnn_fused_kernel(
    const float* __restrict__ x,      // [B,T,D]
    const float* __restrict__ W_ih,   // [H,D]
    const float* __restrict__ W_hh,   // [H,H]
    const float* __restrict__ b_ih,   // [H]
    const float* __restrict__ b_hh,   // [H]
    const float* __restrict__ W_out,  // [D,H]
    const float* __restrict__ b_out,  // [D]
    float* __restrict__ out)          // [B,T,D]
{
    const int lane = threadIdx.x;                 // 0..63
    const int b0   = blockIdx.x * 2;              // two batch elements per wave
    const int b1   = b0 + 1;
    const int row  = (lane < HH) ? lane : (HH - 1);  // clamp idle lanes

    // Shared per-lane weights: row `row` of W_hh, W_ih row, combined bias.
    float w[HH];
    #pragma unroll
    for (int j = 0; j < HH; ++j) w[j] = W_hh[row * HH + j];
    const float wi0 = W_ih[row * DD + 0];
    const float wi1 = W_ih[row * DD + 1];
    const float wi2 = W_ih[row * DD + 2];
    const float bias = b_ih[row] + b_hh[row];

    __shared__ float hsT0[64 * HSTR];  // h transpose buffer, batch 0
    __shared__ float hsT1[64 * HSTR];  // h transpose buffer, batch 1
    __shared__ float wo[3][HH];
    __shared__ float bo[3];
    if (lane < HH) {
        wo[0][lane] = W_out[0 * HH + lane];
        wo[1][lane] = W_out[1 * HH + lane];
        wo[2][lane] = W_out[2 * HH + lane];
    }
    if (lane < 3) bo[lane] = b_out[lane];

    const float* xb0 = x   + (size_t)b0 * TT * DD;
    const float* xb1 = x   + (size_t)b1 * TT * DD;
    float*       yb0 = out + (size_t)b0 * TT * DD;
    float*       yb1 = out + (size_t)b1 * TT * DD;

    float h0 = 0.0f, h1 = 0.0f;

    for (int tile = 0; tile < TT / TILE; ++tile) {
        const int t0 = tile * TILE;

        // Lane l stages x[b, t0+l, 0:3] in registers; broadcast by readlane in the loop.
        float xa0 = 0.0f, xv0 = 0.0f, xc0 = 0.0f;
        float xa1 = 0.0f, xv1 = 0.0f, xc1 = 0.0f;
        if (lane < TILE) {
            const float* xs0 = xb0 + (size_t)(t0 + lane) * DD;
            const float* xs1 = xb1 + (size_t)(t0 + lane) * DD;
            xa0 = xs0[0]; xv0 = xs0[1]; xc0 = xs0[2];
            xa1 = xs1[0]; xv1 = xs1[1]; xc1 = xs1[2];
        }
        __syncthreads();  // previous tile's stage-2 reads of hsT complete

        #pragma unroll 2
        for (int s = 0; s < TILE; ++s) {
            // xp contributions (3 broadcast terms each), interleaved
            float p0 = bcast(xa0, s);
            float q0 = bcast(xa1, s);
            float p1 = bcast(xv0, s);
            float q1 = bcast(xv1, s);
            float p2 = bcast(xc0, s);
            float q2 = bcast(xc1, s);
            float a0 = fmaf(wi0, p0, bias);
            float c0 = fmaf(wi0, q0, bias);
            float a1 = wi1 * p1;
            float c1 = wi1 * q1;
            float a2 = wi2 * p2;
            float c2 = wi2 * q2;
            float a3 = 0.0f;
            float c3 = 0.0f;

            // recurrent matvec: 50 broadcast+fmac pairs per batch, interleaved,
            // 4 accumulators each
            #pragma unroll
            for (int j = 0; j < HH; ++j) {
                float hj0 = bcast(h0, j);
                float hj1 = bcast(h1, j);
                if      ((j & 3) == 0) { a0 = fmaf(w[j], hj0, a0); c0 = fmaf(w[j], hj1, c0); }
                else if ((j & 3) == 1) { a1 = fmaf(w[j], hj0, a1); c1 = fmaf(w[j], hj1, c1); }
                else if ((j & 3) == 2) { a2 = fmaf(w[j], hj0, a2); c2 = fmaf(w[j], hj1, c2); }
                else                   { a3 = fmaf(w[j], hj0, a3); c3 = fmaf(w[j], hj1, c3); }
            }
            h0 = fmaxf((a0 + a1) + (a2 + a3), 0.0f);
            h1 = fmaxf((c0 + c1) + (c2 + c3), 0.0f);

            hsT0[lane * HSTR + s] = h0;
            hsT1[lane * HSTR + s] = h1;
        }
        __syncthreads();  // hsT visible to the transpose read pattern

        // Stage 2: lane s computes y[t0+s, 0:3] for both batches, interleaved
        if (lane < TILE) {
            float y0 = bo[0], y1 = bo[1], y2 = bo[2];
            float z0 = bo[0], z1 = bo[1], z2 = bo[2];
            #pragma unroll
            for (int i = 0; i < HH; ++i) {
                float hv0 = hsT0[i * HSTR + lane];   // consecutive lanes -> consecutive banks
                float hv1 = hsT1[i * HSTR + lane];
                y0 = fmaf(wo[0][i], hv0, y0);
                z0 = fmaf(wo[0][i], hv1, z0);
                y1 = fmaf(wo[1][i], hv0, y1);
                z1 = fmaf(wo[1][i], hv1, z1);
                y2 = fmaf(wo[2][i], hv0, y2);
                z2 = fmaf(wo[2][i], hv1, z2);
            }
            float* yp0 = yb0 + (size_t)(t0 + lane) * DD;
            float* yp1 = yb1 + (size_t)(t0 + lane) * DD;
            yp0[0] = y0; yp0[1] = y1; yp0[2] = y2;
            yp1[0] = z0; yp1[1] = z1; yp1[2] = z2;
        }
    }
}

extern "C" void kernel_launch(void* const* d_in, const int* in_sizes, int n_in,
                              void* d_out, int out_size, void* d_ws, size_t ws_size,
                              hipStream_t stream) {
    const float* x     = (const float*)d_in[0];
    const float* W_ih  = (const float*)d_in[1];
    const float* W_hh  = (const float*)d_in[2];
    const float* b_ih  = (const float*)d_in[3];
    const float* b_hh  = (const float*)d_in[4];
    const float* W_out = (const float*)d_in[5];
    const float* b_out = (const float*)d_in[6];
    float* out = (float*)d_out;

    rnn_fused_kernel<<<BB / 2, 64, 0, stream>>>(x, W_ih, W_hh, b_ih, b_hh, W_out, b_out, out);
}